// Round 1
// baseline (678.006 us; speedup 1.0000x reference)
//
#include <hip/hip_runtime.h>

#define N_EMB 65536
#define DIM   512
#define K_C   256
#define M_TILE 16

// ws layout: ct4 = float4[DIM/4][K_C]  (512 KiB)  |  cnorm = float[K_C] (1 KiB)

__global__ void transpose_centroids(const float* __restrict__ cent,
                                    float4* __restrict__ ct4) {
    const int d4 = blockIdx.x;   // 0..127
    const int k  = threadIdx.x;  // 0..255
    const float* src = cent + (size_t)k * DIM + d4 * 4;
    ct4[d4 * K_C + k] = make_float4(src[0], src[1], src[2], src[3]);
}

__global__ void centroid_norms(const float* __restrict__ cent,
                               float* __restrict__ cnorm) {
    const int k = blockIdx.x;
    const int lane = threadIdx.x;  // 64 threads
    const float4* row = (const float4*)(cent + (size_t)k * DIM);
    float s = 0.f;
    for (int i = lane; i < DIM / 4; i += 64) {
        float4 v = row[i];
        s += v.x * v.x + v.y * v.y + v.z * v.z + v.w * v.w;
    }
    #pragma unroll
    for (int off = 32; off > 0; off >>= 1) s += __shfl_down(s, off, 64);
    if (lane == 0) cnorm[k] = s;
}

__global__ __launch_bounds__(256)
void neg_sampler_main(const float* __restrict__ emb,
                      const float* __restrict__ cent,
                      const float4* __restrict__ ct4,
                      const float* __restrict__ cnorm,
                      float* __restrict__ out) {
    __shared__ float S[M_TILE][K_C];
    __shared__ int idx2_lds[M_TILE];

    const int tid  = threadIdx.x;            // centroid index for this thread
    const int row0 = blockIdx.x * M_TILE;    // first embedding row of this block

    float acc[M_TILE];
    #pragma unroll
    for (int m = 0; m < M_TILE; ++m) acc[m] = 0.f;

    const float* eb = emb + (size_t)row0 * DIM;

    // Hot loop: e-values are wave-uniform -> scalar loads; ct4 loads are
    // coalesced float4 from L2-resident transposed centroids.
    for (int dc = 0; dc < DIM; dc += 8) {
        const float4 ca = ct4[(dc >> 2) * K_C + tid];
        const float4 cb = ct4[((dc >> 2) + 1) * K_C + tid];
        #pragma unroll
        for (int m = 0; m < M_TILE; ++m) {
            const float* ep = eb + m * DIM + dc;
            float a = acc[m];
            a = fmaf(ep[0], ca.x, a);
            a = fmaf(ep[1], ca.y, a);
            a = fmaf(ep[2], ca.z, a);
            a = fmaf(ep[3], ca.w, a);
            a = fmaf(ep[4], cb.x, a);
            a = fmaf(ep[5], cb.y, a);
            a = fmaf(ep[6], cb.z, a);
            a = fmaf(ep[7], cb.w, a);
            acc[m] = a;
        }
    }

    // score = ||c||^2 - 2 e.c   (||e||^2 is constant per row, drops from argmin)
    const float cn = cnorm[tid];
    #pragma unroll
    for (int m = 0; m < M_TILE; ++m) S[m][tid] = fmaf(-2.f, acc[m], cn);
    __syncthreads();

    // Top-2 (smallest) per row with stable smaller-index tiebreak.
    // Wave w handles rows 4w..4w+3.
    const int wave = tid >> 6, lane = tid & 63;
    for (int mm = 0; mm < 4; ++mm) {
        const int m = wave * 4 + mm;
        float v1 = 1e30f, v2 = 1e30f;
        int i1 = -1, i2 = -1;
        #pragma unroll
        for (int j = 0; j < 4; ++j) {
            const int k = lane + 64 * j;
            const float v = S[m][k];
            if (v < v1 || (v == v1 && k < i1)) { v2 = v1; i2 = i1; v1 = v; i1 = k; }
            else if (v < v2 || (v == v2 && k < i2)) { v2 = v; i2 = k; }
        }
        #pragma unroll
        for (int off = 1; off < 64; off <<= 1) {
            const float ov1 = __shfl_xor(v1, off, 64);
            const int   oi1 = __shfl_xor(i1, off, 64);
            const float ov2 = __shfl_xor(v2, off, 64);
            const int   oi2 = __shfl_xor(i2, off, 64);
            if (ov1 < v1 || (ov1 == v1 && oi1 < i1)) { v2 = v1; i2 = i1; v1 = ov1; i1 = oi1; }
            else if (ov1 < v2 || (ov1 == v2 && oi1 < i2)) { v2 = ov1; i2 = oi1; }
            if (ov2 < v1 || (ov2 == v1 && oi2 < i1)) { v2 = v1; i2 = i1; v1 = ov2; i1 = oi2; }
            else if (ov2 < v2 || (ov2 == v2 && oi2 < i2)) { v2 = ov2; i2 = oi2; }
        }
        if (lane == 0) idx2_lds[m] = i2;
    }
    __syncthreads();

    // Gather: out[row0+m] = centroids[idx2[m]]   (coalesced float4 writes)
    for (int i = tid; i < M_TILE * (DIM / 4); i += 256) {
        const int m   = i >> 7;        // DIM/4 == 128
        const int off = i & 127;
        const int c   = idx2_lds[m];
        ((float4*)(out + (size_t)(row0 + m) * DIM))[off] =
            ((const float4*)(cent + (size_t)c * DIM))[off];
    }
}

extern "C" void kernel_launch(void* const* d_in, const int* in_sizes, int n_in,
                              void* d_out, int out_size, void* d_ws, size_t ws_size,
                              hipStream_t stream) {
    const float* emb  = (const float*)d_in[0];
    const float* cent = (const float*)d_in[1];
    // d_in[2] = batch_id, unused.

    float4* ct4  = (float4*)d_ws;
    float* cnorm = (float*)((char*)d_ws + (size_t)(DIM / 4) * K_C * sizeof(float4));

    transpose_centroids<<<DIM / 4, K_C, 0, stream>>>(cent, ct4);
    centroid_norms<<<K_C, 64, 0, stream>>>(cent, cnorm);
    neg_sampler_main<<<N_EMB / M_TILE, 256, 0, stream>>>(emb, cent, ct4, cnorm,
                                                         (float*)d_out);
}